// Round 9
// baseline (12.377 us; speedup 1.0000x reference)
//
#include <hip/hip_runtime.h>

// OneDimEquivalent: T=524288-step contracting scan, single dispatch.
// Parallelization: warm-up windows (W=40; contraction <=0.872/step ->
// ~1.3e-4 z residual). gi(s), s = 1.44k^2 + 0.64u^2, via a single-region
// linear LDS table: s in [0,20.5), h=1/16, 328 cells (baked at COMPILE TIME
// from the reference's 64-node Gauss-Legendre fp32 quadrature; fp64 Newton
// nodes, fp32 casts exactly where the reference casts). Index comes from the
// u-part only (known in advance -> LDS gathers pipeline OFF the serial
// chain); k^2 applied via the baked cell slope: gi = base_t + ck_t*k^2.
//
// This round (overhead-bound regime; kernel-internal ~1.2us of 9.9us):
//  - pre-history zeroing moved under a block-uniform branch (only block 0
//    ever needs it) -- saves ~48 v_cndmask per thread elsewhere;
//  - warm-up split: first 24 steps skip the k^2 slope correction
//    (gi err <=7.4e-4 -> <=3e-5 in k after 16 full steps, ~7e-6 in z).

#define THREADS 256
#define CHUNK   8
#define W_STEPS 40
#define NSTEP   48            // W + CHUNK, 6 groups of 8
#define NCELL   328           // x = 16*s over s in [0, 20.5)

#if __has_builtin(__builtin_amdgcn_fractf)
#define FRACTF(x) __builtin_amdgcn_fractf(x)
#else
#define FRACTF(x) ((x) - floorf(x))
#endif

// ---------------- compile-time math (fp64, constexpr) -----------------------
constexpr double CPI   = 3.14159265358979323846;
constexpr double CLN2H = 0.6931471805599453;
constexpr double CLN2L = 2.3190468138462996e-17;
constexpr double CL2E  = 1.4426950408889634;

constexpr double cexp(double x) {            // x <= 0, |x| < 700
  int n = (int)(x * CL2E - 0.5);             // round-to-nearest (x<=0)
  double r = (x - n * CLN2H) - n * CLN2L;
  double acc = 1.0, term = 1.0;
  for (int k = 1; k <= 13; ++k) { term *= r / k; acc += term; }
  double s = 1.0, b = 2.0;
  int m = -n;                                // n <= 0
  while (m) { if (m & 1) s *= b; b *= b; m >>= 1; }
  return acc / s;
}
constexpr double ccos(double x) {            // |x| <= pi
  double x2 = x * x, acc = 1.0, term = 1.0;
  for (int k = 1; k <= 12; ++k) {
    term *= -x2 / ((2.0 * k - 1.0) * (2.0 * k));
    acc += term;
  }
  return acc;
}
constexpr double csqrt(double s) {           // s in [0, 64)
  if (s <= 0.0) return 0.0;
  double r = s > 1.0 ? s : 1.0;
  for (int it = 0; it < 20; ++it) r = 0.5 * (r + s / r);
  return r;
}

// Gauss-Legendre order 64: positive nodes + folded pair weights, with fp32
// casts exactly where the reference casts (nodes/weights scaled by A=5).
struct GL32 { double z[32]; double w2[32]; };
constexpr GL32 make_gl() {
  GL32 g{};
  for (int i = 0; i < 32; ++i) {
    double x = ccos(CPI * ((double)i + 0.75) / 64.5);
    double dp = 1.0;
    for (int it = 0; it < 5; ++it) {         // Newton on P_64, fp64
      double p0 = 1.0, p1 = x;
      for (int j = 2; j <= 64; ++j) {
        double p2 = ((2.0 * j - 1.0) * x * p1 - (double)(j - 1) * p0) / j;
        p0 = p1; p1 = p2;
      }
      dp = 64.0 * (x * p1 - p0) / (x * x - 1.0);
      x -= p1 / dp;
    }
    double w = 2.0 / ((1.0 - x * x) * dp * dp);
    float zn = (float)(5.0 * x);             // reference: fp32 node
    float wn = (float)(5.0 * w);             // reference: fp32 weight
    g.z[i]  = (double)zn;
    // folded +/- pair: 2 * w * exp(-z^2/2) / (2*pi)
    g.w2[i] = 2.0 * (double)wn * cexp(-0.5 * (double)zn * (double)zn)
              * 0.15915494309189535;
  }
  return g;
}
constexpr GL32 GLC = make_gl();

// g(s) = sum_n w2[n] * sech^2(sqrt(s)*z[n]);  sech^2(a) = 4e/(1+e)^2,
// e = exp(-2a). Cutoff a>12.5 (contribution <1e-10).
constexpr float tab_entry(double s) {
  double d2 = 2.0 * csqrt(s);
  double acc = 0.0;
  for (int n = 0; n < 32; ++n) {
    double a = d2 * GLC.z[n];
    if (a < 12.5) {
      double e = cexp(-a);
      double t = 1.0 + e;
      acc += GLC.w2[n] * (4.0 * e / (t * t));
    }
  }
  return (float)acc;
}

// Fat cells: (g0, slope, ck = 23.04*slope, pad). Built in 4 constexpr
// quarters to stay under per-initializer constexpr-step limits.
struct alignas(16) Cell { float g0, sl, ck, pad; };
struct alignas(16) Quarter { Cell c[82]; };
constexpr Quarter make_q(int b) {
  Quarter q{};
  float smp[83]{};
  for (int j = 0; j < 83; ++j)
    smp[j] = tab_entry((double)(b + j) * (1.0 / 16.0));
  for (int j = 0; j < 82; ++j) {
    float sl = smp[j + 1] - smp[j];
    q.c[j] = Cell{smp[j], sl, 23.04f * sl, 0.0f};   // 1.44/h = 23.04
  }
  return q;
}
constexpr Quarter QA = make_q(0), QB = make_q(82), QC = make_q(164),
                  QD = make_q(246);
struct alignas(16) Tab { Cell c[NCELL]; };
constexpr Tab make_tab() {
  Tab t{};
  for (int j = 0; j < 82; ++j) {
    t.c[j]       = QA.c[j];
    t.c[82 + j]  = QB.c[j];
    t.c[164 + j] = QC.c[j];
    t.c[246 + j] = QD.c[j];
  }
  return t;
}
__device__ constexpr Tab TAB = make_tab();

// ---------------- scan pieces -----------------------------------------------
// prep: per-step table lookup + linearization constants (independent of k,v)
__device__ __forceinline__ void prep8(const float* uu, const float4* q,
                                      float* base, float* ck) {
#pragma unroll
  for (int j = 0; j < 8; ++j) {
    float x = fminf(10.24f * uu[j] * uu[j], 327.99f);  // 16 * 0.64 * u^2
    int   i = (int)x;
    float f = FRACTF(x);
    float4 c = q[i];                          // one ds_read_b128
    base[j] = fmaf(f, c.y, c.x);
    ck[j]   = c.z;
  }
}
// run: the serial recurrence.
// KCORR: apply the k^2 slope correction (gi = base + ck*k^2) -- needed only
// near the emit region; early warm-up uses gi = base (k is tiny, error ~7e-6
// in z after 16 corrected steps). EMIT: record z.
template <bool KCORR, bool EMIT>
__device__ __forceinline__ void run8(const float* uu, const float* base,
                                     const float* ck, float& k, float& v,
                                     float* z) {
#pragma unroll
  for (int j = 0; j < 8; ++j) {
    float th = fmaf(0.18f, k, 0.1f * v);      // parallel to gi path
    float gi = KCORR ? fmaf(ck[j], k * k, base[j]) : base[j];
    float kn = fmaf(gi, th, 0.8f * k);
    v = fmaf(0.2f, uu[j], 0.8f * v);
    if (EMIT) z[j] = 0.7f * gi * kn;
    k = kn;
  }
}

__global__ __launch_bounds__(THREADS, 1) void scan1_kernel(
    const float* __restrict__ u, float* __restrict__ out) {
  __shared__ float4 q[NCELL];                 // 5.25 KiB

  const int tid = threadIdx.x;
  const int t   = blockIdx.x * THREADS + tid;
  const int g8  = t * CHUNK;
  if (t == 0) out[0] = 0.0f;

  // ---- issue all u loads first (address-clamped; fixup only in block 0) ---
  const int base4 = (g8 - W_STEPS) >> 2;
  const float4* __restrict__ up = (const float4*)u;
  float uu[NSTEP];
#pragma unroll
  for (int j = 0; j < NSTEP / 4; ++j) {
    float4 w = up[max(base4 + j, 0)];
    uu[4 * j + 0] = w.x;
    uu[4 * j + 1] = w.y;
    uu[4 * j + 2] = w.z;
    uu[4 * j + 3] = w.w;
  }
  if (blockIdx.x == 0) {                      // block-uniform: s_cbranch skip
    const int nz = W_STEPS - g8;              // leading pre-history steps
#pragma unroll
    for (int j = 0; j < W_STEPS; ++j)
      if (j < nz) uu[j] = 0.0f;
  }

  // ---- table: copy .rodata -> LDS -----------------------------------------
  const float4* __restrict__ tsrc = reinterpret_cast<const float4*>(TAB.c);
  for (int i = tid; i < NCELL; i += THREADS) q[i] = tsrc[i];
  __syncthreads();

  // ---- scan: 3 cheap + 2 full warm-up groups + 1 emit group ---------------
  float k = 0.0f, v = 0.0f, z[8];
  float B0[8], C0[8], B1[8], C1[8];
  prep8(uu + 0,  q, B0, C0);
  prep8(uu + 8,  q, B1, C1);
  run8<false, false>(uu + 0,  B0, C0, k, v, z);
  prep8(uu + 16, q, B0, C0);
  run8<false, false>(uu + 8,  B1, C1, k, v, z);
  prep8(uu + 24, q, B1, C1);
  run8<false, false>(uu + 16, B0, C0, k, v, z);
  prep8(uu + 32, q, B0, C0);
  run8<true,  false>(uu + 24, B1, C1, k, v, z);
  prep8(uu + 40, q, B1, C1);
  run8<true,  false>(uu + 32, B0, C0, k, v, z);
  run8<true,  true >(uu + 40, B1, C1, k, v, z);

#pragma unroll
  for (int j = 0; j < 8; ++j) out[g8 + 1 + j] = z[j];
}

extern "C" void kernel_launch(void* const* d_in, const int* in_sizes, int n_in,
                              void* d_out, int out_size, void* d_ws,
                              size_t ws_size, hipStream_t stream) {
  const float* u = (const float*)d_in[0];
  float* out = (float*)d_out;
  const int T = in_sizes[0];                  // 524288
  const int nblock = T / (CHUNK * THREADS);   // 256
  scan1_kernel<<<nblock, THREADS, 0, stream>>>(u, out);
}

// Round 10
// 10.220 us; speedup vs baseline: 1.2110x; 1.2110x over previous
//
#include <hip/hip_runtime.h>

// OneDimEquivalent: T=524288-step contracting scan, single dispatch.
// Parallelization: warm-up windows (W=40; contraction <=0.872/step ->
// ~1.3e-4 z residual). gi(s), s = 1.44k^2 + 0.64u^2, via a single-region
// linear LDS table: s in [0,20.5), h=1/16, 328 cells (baked at COMPILE TIME
// from the reference's 64-node Gauss-Legendre fp32 quadrature; fp64 Newton
// nodes, fp32 casts exactly where the reference casts). Index comes from the
// u-part only (known in advance -> LDS gathers pipeline OFF the serial
// chain); k^2 applied via the baked cell slope: gi = base_t + ck_t*k^2.
// Serial chain per step: k*k -> fma -> fma.
//
// R9's micro-trims (block-0-branch pre-history fixup, KCORR warm-up split)
// REGRESSED 9.94 -> 12.38 us; this is the exact R8 form (9.94 us, absmax
// 4.88e-4). Kernel is overhead-bound: replay/launch floor ~8.6-8.8 us,
// kernel-internal ~1.2 us.

#define THREADS 256
#define CHUNK   8
#define W_STEPS 40
#define NSTEP   48            // W + CHUNK, 6 groups of 8
#define NCELL   328           // x = 16*s over s in [0, 20.5)

#if __has_builtin(__builtin_amdgcn_fractf)
#define FRACTF(x) __builtin_amdgcn_fractf(x)
#else
#define FRACTF(x) ((x) - floorf(x))
#endif

// ---------------- compile-time math (fp64, constexpr) -----------------------
constexpr double CPI   = 3.14159265358979323846;
constexpr double CLN2H = 0.6931471805599453;
constexpr double CLN2L = 2.3190468138462996e-17;
constexpr double CL2E  = 1.4426950408889634;

constexpr double cexp(double x) {            // x <= 0, |x| < 700
  int n = (int)(x * CL2E - 0.5);             // round-to-nearest (x<=0)
  double r = (x - n * CLN2H) - n * CLN2L;
  double acc = 1.0, term = 1.0;
  for (int k = 1; k <= 13; ++k) { term *= r / k; acc += term; }
  double s = 1.0, b = 2.0;
  int m = -n;                                // n <= 0
  while (m) { if (m & 1) s *= b; b *= b; m >>= 1; }
  return acc / s;
}
constexpr double ccos(double x) {            // |x| <= pi
  double x2 = x * x, acc = 1.0, term = 1.0;
  for (int k = 1; k <= 12; ++k) {
    term *= -x2 / ((2.0 * k - 1.0) * (2.0 * k));
    acc += term;
  }
  return acc;
}
constexpr double csqrt(double s) {           // s in [0, 64)
  if (s <= 0.0) return 0.0;
  double r = s > 1.0 ? s : 1.0;
  for (int it = 0; it < 20; ++it) r = 0.5 * (r + s / r);
  return r;
}

// Gauss-Legendre order 64: positive nodes + folded pair weights, with fp32
// casts exactly where the reference casts (nodes/weights scaled by A=5).
struct GL32 { double z[32]; double w2[32]; };
constexpr GL32 make_gl() {
  GL32 g{};
  for (int i = 0; i < 32; ++i) {
    double x = ccos(CPI * ((double)i + 0.75) / 64.5);
    double dp = 1.0;
    for (int it = 0; it < 5; ++it) {         // Newton on P_64, fp64
      double p0 = 1.0, p1 = x;
      for (int j = 2; j <= 64; ++j) {
        double p2 = ((2.0 * j - 1.0) * x * p1 - (double)(j - 1) * p0) / j;
        p0 = p1; p1 = p2;
      }
      dp = 64.0 * (x * p1 - p0) / (x * x - 1.0);
      x -= p1 / dp;
    }
    double w = 2.0 / ((1.0 - x * x) * dp * dp);
    float zn = (float)(5.0 * x);             // reference: fp32 node
    float wn = (float)(5.0 * w);             // reference: fp32 weight
    g.z[i]  = (double)zn;
    // folded +/- pair: 2 * w * exp(-z^2/2) / (2*pi)
    g.w2[i] = 2.0 * (double)wn * cexp(-0.5 * (double)zn * (double)zn)
              * 0.15915494309189535;
  }
  return g;
}
constexpr GL32 GLC = make_gl();

// g(s) = sum_n w2[n] * sech^2(sqrt(s)*z[n]);  sech^2(a) = 4e/(1+e)^2,
// e = exp(-2a). Cutoff a>12.5 (contribution <1e-10).
constexpr float tab_entry(double s) {
  double d2 = 2.0 * csqrt(s);
  double acc = 0.0;
  for (int n = 0; n < 32; ++n) {
    double a = d2 * GLC.z[n];
    if (a < 12.5) {
      double e = cexp(-a);
      double t = 1.0 + e;
      acc += GLC.w2[n] * (4.0 * e / (t * t));
    }
  }
  return (float)acc;
}

// Fat cells: (g0, slope, ck = 23.04*slope, pad). Built in 4 constexpr
// quarters to stay under per-initializer constexpr-step limits.
struct alignas(16) Cell { float g0, sl, ck, pad; };
struct alignas(16) Quarter { Cell c[82]; };
constexpr Quarter make_q(int b) {
  Quarter q{};
  float smp[83]{};
  for (int j = 0; j < 83; ++j)
    smp[j] = tab_entry((double)(b + j) * (1.0 / 16.0));
  for (int j = 0; j < 82; ++j) {
    float sl = smp[j + 1] - smp[j];
    q.c[j] = Cell{smp[j], sl, 23.04f * sl, 0.0f};   // 1.44/h = 23.04
  }
  return q;
}
constexpr Quarter QA = make_q(0), QB = make_q(82), QC = make_q(164),
                  QD = make_q(246);
struct alignas(16) Tab { Cell c[NCELL]; };
constexpr Tab make_tab() {
  Tab t{};
  for (int j = 0; j < 82; ++j) {
    t.c[j]       = QA.c[j];
    t.c[82 + j]  = QB.c[j];
    t.c[164 + j] = QC.c[j];
    t.c[246 + j] = QD.c[j];
  }
  return t;
}
__device__ constexpr Tab TAB = make_tab();

// ---------------- scan pieces -----------------------------------------------
// prep: per-step table lookup + linearization constants (independent of k,v)
__device__ __forceinline__ void prep8(const float* uu, const float4* q,
                                      float* base, float* ck) {
#pragma unroll
  for (int j = 0; j < 8; ++j) {
    float x = fminf(10.24f * uu[j] * uu[j], 327.99f);  // 16 * 0.64 * u^2
    int   i = (int)x;
    float f = FRACTF(x);
    float4 c = q[i];                          // one ds_read_b128
    base[j] = fmaf(f, c.y, c.x);
    ck[j]   = c.z;
  }
}
// run: the serial recurrence; critical chain = mul,fma,fma per step
template <bool EMIT>
__device__ __forceinline__ void run8(const float* uu, const float* base,
                                     const float* ck, float& k, float& v,
                                     float* z) {
#pragma unroll
  for (int j = 0; j < 8; ++j) {
    float th = fmaf(0.18f, k, 0.1f * v);      // parallel to gi path
    float gi = fmaf(ck[j], k * k, base[j]);
    float kn = fmaf(gi, th, 0.8f * k);
    v = fmaf(0.2f, uu[j], 0.8f * v);
    if (EMIT) z[j] = 0.7f * gi * kn;
    k = kn;
  }
}

__global__ __launch_bounds__(THREADS, 1) void scan1_kernel(
    const float* __restrict__ u, float* __restrict__ out) {
  __shared__ float4 q[NCELL];                 // 5.25 KiB

  const int tid = threadIdx.x;
  const int t   = blockIdx.x * THREADS + tid;
  const int g8  = t * CHUNK;
  if (t == 0) out[0] = 0.0f;

  // ---- issue all u loads first --------------------------------------------
  const int base4 = (g8 - W_STEPS) >> 2;
  const float4* __restrict__ up = (const float4*)u;
  float uu[NSTEP];
#pragma unroll
  for (int j = 0; j < NSTEP / 4; ++j) {
    int idx = base4 + j;
    float4 w = up[max(idx, 0)];
    bool ok = (idx >= 0);                     // first block: u=0 pre-history
    uu[4 * j + 0] = ok ? w.x : 0.0f;
    uu[4 * j + 1] = ok ? w.y : 0.0f;
    uu[4 * j + 2] = ok ? w.z : 0.0f;
    uu[4 * j + 3] = ok ? w.w : 0.0f;
  }

  // ---- table: copy .rodata -> LDS -----------------------------------------
  const float4* __restrict__ tsrc = reinterpret_cast<const float4*>(TAB.c);
  for (int i = tid; i < NCELL; i += THREADS) q[i] = tsrc[i];
  __syncthreads();

  // ---- scan: 6 groups of 8 steps, lookups pipelined 2 groups ahead --------
  float k = 0.0f, v = 0.0f, z[8];
  float B0[8], C0[8], B1[8], C1[8];
  prep8(uu + 0,  q, B0, C0);
  prep8(uu + 8,  q, B1, C1);
  run8<false>(uu + 0,  B0, C0, k, v, z);
  prep8(uu + 16, q, B0, C0);
  run8<false>(uu + 8,  B1, C1, k, v, z);
  prep8(uu + 24, q, B1, C1);
  run8<false>(uu + 16, B0, C0, k, v, z);
  prep8(uu + 32, q, B0, C0);
  run8<false>(uu + 24, B1, C1, k, v, z);
  prep8(uu + 40, q, B1, C1);
  run8<false>(uu + 32, B0, C0, k, v, z);
  run8<true>(uu + 40, B1, C1, k, v, z);

#pragma unroll
  for (int j = 0; j < 8; ++j) out[g8 + 1 + j] = z[j];
}

extern "C" void kernel_launch(void* const* d_in, const int* in_sizes, int n_in,
                              void* d_out, int out_size, void* d_ws,
                              size_t ws_size, hipStream_t stream) {
  const float* u = (const float*)d_in[0];
  float* out = (float*)d_out;
  const int T = in_sizes[0];                  // 524288
  const int nblock = T / (CHUNK * THREADS);   // 256
  scan1_kernel<<<nblock, THREADS, 0, stream>>>(u, out);
}